// Round 11
// baseline (137.030 us; speedup 1.0000x reference)
//
#include <hip/hip_runtime.h>
#include <math.h>

#define NTOK   16384
#define HDIM   1024
#define HHALF  512
#define NE     16
#define PI_F   3.14159265358979323846f

// d_out layout (concatenated reference outputs, all f32; indices stored as float)
#define OFF_TP  0
#define OFF_TI  (NTOK * 2)
#define OFF_DEC (NTOK * 4)
#define OFF_PH  (OFF_DEC + NTOK * NE)
#define OFF_PR  (OFF_PH + NTOK * NE)

typedef _Float16 half8 __attribute__((ext_vector_type(8)));
typedef _Float16 half4 __attribute__((ext_vector_type(4)));
typedef short    bf8   __attribute__((ext_vector_type(8)));
typedef short    bf4   __attribute__((ext_vector_type(4)));
typedef float f32x16 __attribute__((ext_vector_type(16)));
typedef float f32x4 __attribute__((ext_vector_type(4)));

#define SCALE      2048.0f
#define SCALE_INV  (1.0f / 2048.0f)
#define MFMA_F16(a,b,c)  __builtin_amdgcn_mfma_f32_32x32x16_f16(a,b,c,0,0,0)
#define MFMA_BF16(a,b,c) __builtin_amdgcn_mfma_f32_32x32x16_bf16(a,b,c,0,0,0)
#define MFMA16(a,b,c)    __builtin_amdgcn_mfma_f32_16x16x32_f16(a,b,c,0,0,0)

// lgkm-only barrier: LDS visibility; vmcnt stays counted (prefetches in flight).
#define BAR() asm volatile("s_waitcnt lgkmcnt(0)\n\ts_barrier" ::: "memory")

__device__ __forceinline__ float gelu_exact(float x) {
    return 0.5f * x * (1.0f + erff(x * 0.70710678118654752440f));
}
__device__ __forceinline__ short f32_to_bf16_bits(float f) {
    unsigned u = __builtin_bit_cast(unsigned, f);
    u += 0x7FFFu + ((u >> 16) & 1u);
    return (short)(u >> 16);
}

// ---------------------------------------------------------------------------
// Prologue: W image in ws. u = (((ph*32+kc)*8+sl)*8+f)*64+l, f = nf*4+kh*2+pl.
// col = sl*64+nf*32+(l&31); k = kc*32+kh*16+(l>>5)*8+j.
// pl=0: f16(W) bits; pl=1: bf16(W - f16(W)) bits (RAW residual, no scale).
// ---------------------------------------------------------------------------
__global__ void __launch_bounds__(256)
qir_wtrans(const float* __restrict__ w1a, const float* __restrict__ w1p,
           short* __restrict__ wt)
{
    int u = blockIdx.x * 256 + threadIdx.x;   // 0..262143
    int l  = u & 63;
    int f  = (u >> 6) & 7;
    int sl = (u >> 9) & 7;
    int kc = (u >> 12) & 31;
    int ph = u >> 17;
    int nf = f >> 2, kh = (f >> 1) & 1, pl = f & 1;
    int col = sl * 64 + nf * 32 + (l & 31);
    int k0  = kc * 32 + kh * 16 + (l >> 5) * 8;
    const float* __restrict__ W = ph ? w1p : w1a;
    bf8 v;
    #pragma unroll
    for (int j = 0; j < 8; ++j) {
        float x = W[(size_t)(k0 + j) * HHALF + col];
        _Float16 h = (_Float16)x;
        v[j] = pl ? f32_to_bf16_bits(x - (float)h)
                  : __builtin_bit_cast(short, h);
    }
    *(bf8*)&wt[(size_t)u * 8] = v;
}

// ---------------------------------------------------------------------------
// Fused GEMM + epilogue. Block = 32 tokens x 512 cols x one phase.
// 4 waves, wave tile 32x128. Single scale-2048 accumulator, 3 products:
//   P1 f16(2048*xh, wh) + P2 f16(2048*xl, wh) + P3 bf16(2048*xh_b, wlo_b).
// B chunked (kh0 held / kh1 issued at top / next-kh0 issued mid). A staged in
// 2x6KB LDS (3 planes: xh', xl', xb). ph=0 blocks run the FULL epilogue for
// their 32 tokens in-block; ph=1 blocks apply tanh. No atomics, no 2nd kernel.
// LDS 17408: A dbuf [0,12K); epilogue H [w*2K, 8K), P [8K,16K), cs/sn [16K,+960).
// ---------------------------------------------------------------------------
__global__ void __launch_bounds__(256, 2)
qir_gemm(const float* __restrict__ xg, const short* __restrict__ wt,
         const float* __restrict__ b1a, const float* __restrict__ w2a, const float* __restrict__ b2a,
         const float* __restrict__ b1p, const float* __restrict__ w2p, const float* __restrict__ b2p,
         const float* __restrict__ ent, float* __restrict__ out)
{
    extern __shared__ char smem[];
    const int tid = threadIdx.x;
    const int l  = tid & 63;
    const int w  = tid >> 6;          // wave 0..3 owns cols w*128..+127
    const int bid  = blockIdx.x;
    const int mblk = bid & 511;
    const int ph   = bid >> 9;
    const int tok0 = mblk * 32;

    const float* __restrict__ b1 = ph ? b1p : b1a;
    const float* __restrict__ w2 = ph ? w2p : w2a;
    const float* __restrict__ b2 = ph ? b2p : b2a;
    const short* __restrict__ wtp = wt + ((size_t)ph << 20);

    float* const cs = (float*)(smem + 16384);
    float* const sn = cs + 120;
    if (tid < 120) {
        int rem = tid, i = 0;
        while (rem >= 15 - i) { rem -= 15 - i; ++i; }
        int j = i + 1 + rem;
        float ang = ent[i * NE + j] * 0.5f;
        cs[tid] = cosf(ang);
        sn[tid] = sinf(ang);
    }

    // A staging: thread -> (row r 0..31, k-quad kq 0..7)
    const int r  = tid >> 3;
    const int kq = tid & 7;
    const float* __restrict__ aptr = xg + (size_t)(tok0 + r) * HDIM + kq * 4;
    // chunk(kh,oct,pl) = ((kh*2+oct)*3+pl)*512 ; buf = 6KB
    const int a_w  = ((kq >> 2) * 2 + ((kq >> 1) & 1)) * 3 * 512 + r * 16 + (kq & 1) * 8;
    const int a_rd = (l >> 5) * 3 * 512 + (l & 31) * 16;   // + kh*3072, +512 lo, +1024 xb

    f32x16 acc[4];
    #pragma unroll
    for (int g = 0; g < 4; ++g)
        #pragma unroll
        for (int rg = 0; rg < 16; ++rg) acc[g][rg] = 0.0f;

    half8 Bch[4], Bdh[4];
    bf8   Bcl[4], Bdl[4];
    float4 xw, xl4;

    // B frag offset (short units within ph image): g = sli*2+nf
#define BOFF(KC, KH, G, PL) \
    ((((size_t)((KC) * 8 + (2 * w + ((G) >> 1))) * 8) + ((G) & 1) * 4 + (KH) * 2 + (PL)) * 512 + (size_t)l * 8)

    auto stageA = [&](char* buf, float4 v) {
        _Float16 h0 = (_Float16)v.x, h1 = (_Float16)v.y,
                 h2 = (_Float16)v.z, h3 = (_Float16)v.w;
        const _Float16 S = (_Float16)SCALE;
        half4 hi = {(_Float16)(h0 * S), (_Float16)(h1 * S),
                    (_Float16)(h2 * S), (_Float16)(h3 * S)};
        half4 lo = {(_Float16)((v.x - (float)h0) * SCALE),
                    (_Float16)((v.y - (float)h1) * SCALE),
                    (_Float16)((v.z - (float)h2) * SCALE),
                    (_Float16)((v.w - (float)h3) * SCALE)};
        bf4 hb = {f32_to_bf16_bits((float)h0 * SCALE),
                  f32_to_bf16_bits((float)h1 * SCALE),
                  f32_to_bf16_bits((float)h2 * SCALE),
                  f32_to_bf16_bits((float)h3 * SCALE)};
        *(half4*)(buf + a_w)        = hi;
        *(half4*)(buf + a_w + 512)  = lo;
        *(bf4*)  (buf + a_w + 1024) = hb;
    };

    char* const Ab0 = smem;
    char* const Ab1 = smem + 6144;

    // prologue: stage A(0), preload B kh0(0), prefetch x(1)
    stageA(Ab0, *(const float4*)aptr);
    #pragma unroll
    for (int g = 0; g < 4; ++g) {
        Bch[g] = *(const half8*)&wtp[BOFF(0, 0, g, 0)];
        Bcl[g] = *(const bf8*)  &wtp[BOFF(0, 0, g, 1)];
    }
    xw = *(const float4*)(aptr + 32);
    BAR();

    auto kstep = [&](int kc, char* Acur, char* Anxt, float4& xcur, float4& xnxt) {
        // issue kh1 frags of this kstep + next-next x (in flight across BAR)
        #pragma unroll
        for (int g = 0; g < 4; ++g) {
            Bdh[g] = *(const half8*)&wtp[BOFF(kc, 1, g, 0)];
            Bdl[g] = *(const bf8*)  &wtp[BOFF(kc, 1, g, 1)];
        }
        if (kc + 2 < 32) xnxt = *(const float4*)(aptr + (kc + 2) * 32);

        // kh0 MFMAs (Bch loaded one kstep ago)
        {
            const char* A0 = Acur + a_rd;
            half8 xh = *(const half8*)(A0);
            half8 xl = *(const half8*)(A0 + 512);
            bf8   xb = *(const bf8*)  (A0 + 1024);
            #pragma unroll
            for (int g = 0; g < 4; ++g) {
                acc[g] = MFMA_F16(xh, Bch[g], acc[g]);
                acc[g] = MFMA_F16(xl, Bch[g], acc[g]);
                acc[g] = MFMA_BF16(xb, Bcl[g], acc[g]);
            }
        }
        // mid: issue next kstep's kh0 frags
        if (kc + 1 < 32) {
            #pragma unroll
            for (int g = 0; g < 4; ++g) {
                Bch[g] = *(const half8*)&wtp[BOFF(kc + 1, 0, g, 0)];
                Bcl[g] = *(const bf8*)  &wtp[BOFF(kc + 1, 0, g, 1)];
            }
        }
        // kh1 MFMAs
        {
            const char* A1 = Acur + 3072 + a_rd;
            half8 xh = *(const half8*)(A1);
            half8 xl = *(const half8*)(A1 + 512);
            bf8   xb = *(const bf8*)  (A1 + 1024);
            #pragma unroll
            for (int g = 0; g < 4; ++g) {
                acc[g] = MFMA_F16(xh, Bdh[g], acc[g]);
                acc[g] = MFMA_F16(xl, Bdh[g], acc[g]);
                acc[g] = MFMA_BF16(xb, Bdl[g], acc[g]);
            }
        }
        if (kc + 1 < 32) stageA(Anxt, xcur);
        BAR();
    };

    for (int kk = 0; kk < 16; ++kk) {
        kstep(2 * kk,     Ab0, Ab1, xw, xl4);
        kstep(2 * kk + 1, Ab1, Ab0, xl4, xw);
    }
#undef BOFF

    // combine scale + bias + exact gelu
    #pragma unroll
    for (int g = 0; g < 4; ++g) {
        const float bb = b1[w * 128 + g * 32 + (l & 31)];
        #pragma unroll
        for (int rg = 0; rg < 16; ++rg)
            acc[g][rg] = gelu_exact(acc[g][rg] * SCALE_INV + bb);
    }

    // ---- fused GEMM2: wave contracts its 128 h-cols for its 32 rows ----
    char* const Hw = smem + w * 2048;            // [4 oct][32 rows][16B]
    char* const hb = Hw + ((l >> 3) & 3) * 512 + (l & 7) * 2;
    float* const P = (float*)(smem + 8192);      // [4 waves][32 tok][16 e]

    f32x4 acc2[2], acc2s[2];
    #pragma unroll
    for (int m16 = 0; m16 < 2; ++m16)
        #pragma unroll
        for (int rg = 0; rg < 4; ++rg) { acc2[m16][rg] = 0.f; acc2s[m16][rg] = 0.f; }

    #pragma unroll
    for (int g = 0; g < 4; ++g) {
        half8 w2h, w2l;
        #pragma unroll
        for (int j = 0; j < 8; ++j) {
            int kg = w * 128 + g * 32 + (l >> 4) * 8 + j;
            float vv = w2[(size_t)kg * NE + (l & 15)];
            _Float16 hh = (_Float16)vv;
            w2h[j] = hh;
            w2l[j] = (_Float16)((vv - (float)hh) * SCALE);
        }
        // hi pass
        #pragma unroll
        for (int rg = 0; rg < 16; ++rg) {
            int row0 = (rg & 3) + 8 * (rg >> 2) + 4 * (l >> 5);
            *(_Float16*)(hb + row0 * 16) = (_Float16)acc[g][rg];
        }
        #pragma unroll
        for (int m16 = 0; m16 < 2; ++m16) {
            half8 a2 = *(const half8*)(Hw + (l >> 4) * 512 +
                                       (m16 * 16 + (l & 15)) * 16);
            acc2[m16]  = MFMA16(a2, w2h, acc2[m16]);
            acc2s[m16] = MFMA16(a2, w2l, acc2s[m16]);
        }
        // lo pass
        #pragma unroll
        for (int rg = 0; rg < 16; ++rg) {
            int row0 = (rg & 3) + 8 * (rg >> 2) + 4 * (l >> 5);
            float vv = acc[g][rg];
            _Float16 hh = (_Float16)vv;
            *(_Float16*)(hb + row0 * 16) = (_Float16)(vv - (float)hh);
        }
        #pragma unroll
        for (int m16 = 0; m16 < 2; ++m16) {
            half8 a2 = *(const half8*)(Hw + (l >> 4) * 512 +
                                       (m16 * 16 + (l & 15)) * 16);
            acc2[m16] = MFMA16(a2, w2h, acc2[m16]);
        }
    }

    #pragma unroll
    for (int m16 = 0; m16 < 2; ++m16)
        #pragma unroll
        for (int rg = 0; rg < 4; ++rg) {
            int row = m16 * 16 + ((l >> 4) << 2) + rg;
            P[w * 512 + row * 16 + (l & 15)] =
                acc2[m16][rg] + acc2s[m16][rg] * SCALE_INV;
        }
    __syncthreads();

    // reduce 4 waves; ph=1 -> tanh write; ph=0 -> stash in P[0] then epilogue
    #pragma unroll
    for (int rep = 0; rep < 2; ++rep) {
        int oi = tid + rep * 256;
        int t = oi >> 4, e = oi & 15;
        float sum = b2[e]
                  + P[t * 16 + e] + P[512 + t * 16 + e]
                  + P[1024 + t * 16 + e] + P[1536 + t * 16 + e];
        if (ph) out[OFF_PH + (size_t)(tok0 + t) * NE + e] = tanhf(sum) * PI_F;
        else    P[t * 16 + e] = sum;
    }

    if (!ph) {
        __syncthreads();
        if (tid < 32) {
            const int token = tok0 + tid;
            float a[16];
            #pragma unroll
            for (int e = 0; e < 16; ++e) a[e] = P[tid * 16 + e];

            float m = fabsf(a[0]);
            #pragma unroll
            for (int e = 1; e < 16; ++e) m = fmaxf(m, fabsf(a[e]));
            float ssum = 0.0f;
            #pragma unroll
            for (int e = 0; e < 16; ++e) { a[e] = expf(fabsf(a[e]) - m); ssum += a[e]; }
            float inv = 1.0f / ssum;
            #pragma unroll
            for (int e = 0; e < 16; ++e) a[e] = sqrtf(a[e] * inv);

            {
                int p = 0;
                #pragma unroll
                for (int i = 0; i < 16; ++i)
                    #pragma unroll
                    for (int j = i + 1; j < 16; ++j) {
                        float c = cs[p], s = sn[p]; ++p;
                        float ai = a[i], aj = a[j];
                        a[i] = c * ai - s * aj;
                        a[j] = s * ai + c * aj;
                    }
            }

            #pragma unroll
            for (int q = 0; q < 4; ++q)
                *(float4*)&out[OFF_DEC + (size_t)token * NE + q * 4] =
                    make_float4(a[q*4], a[q*4+1], a[q*4+2], a[q*4+3]);

            float pr[16];
            float s2 = 0.0f;
            #pragma unroll
            for (int e = 0; e < 16; ++e) { pr[e] = a[e] * a[e]; s2 += pr[e]; }
            float inv2 = 1.0f / fmaxf(s2, 1e-12f);
            #pragma unroll
            for (int e = 0; e < 16; ++e) pr[e] *= inv2;
            #pragma unroll
            for (int q = 0; q < 4; ++q)
                *(float4*)&out[OFF_PR + (size_t)token * NE + q * 4] =
                    make_float4(pr[q*4], pr[q*4+1], pr[q*4+2], pr[q*4+3]);

            float bv = pr[0]; int bi = 0;
            #pragma unroll
            for (int e = 1; e < 16; ++e) if (pr[e] > bv) { bv = pr[e]; bi = e; }
            float sv = -1.0f; int si = 0;
            #pragma unroll
            for (int e = 0; e < 16; ++e) if (e != bi && pr[e] > sv) { sv = pr[e]; si = e; }
            float ts = fmaxf(fabsf(bv) + fabsf(sv), 1e-12f);
            out[OFF_TP + (size_t)token * 2 + 0] = bv / ts;
            out[OFF_TP + (size_t)token * 2 + 1] = sv / ts;
            out[OFF_TI + (size_t)token * 2 + 0] = (float)bi;
            out[OFF_TI + (size_t)token * 2 + 1] = (float)si;
        }
    }
}

// ---------------------------------------------------------------------------
// Fallback (R1 kernel, raw-output variant) if ws too small for the image.
// ---------------------------------------------------------------------------
__global__ void __launch_bounds__(512)
qir_mlp(const float* __restrict__ xg,
        const float* __restrict__ w1a, const float* __restrict__ b1a,
        const float* __restrict__ w2a, const float* __restrict__ b2a,
        const float* __restrict__ w1p, const float* __restrict__ b1p,
        const float* __restrict__ w2p, const float* __restrict__ b2p,
        float* __restrict__ out)
{
    __shared__ float sh_w[16][HHALF];
    __shared__ float sh_x[16][68];

    const int tid  = threadIdx.x;
    const int cg   = tid & 63;
    const int tg   = tid >> 6;
    const int tok0 = blockIdx.x * 64;
    const int cA   = cg * 4;
    const int cB   = 256 + cg * 4;

    for (int phase = 0; phase < 2; ++phase) {
        const float* __restrict__ w1 = phase ? w1p : w1a;
        const float* __restrict__ b1 = phase ? b1p : b1a;
        const float* __restrict__ w2 = phase ? w2p : w2a;
        const float* __restrict__ b2 = phase ? b2p : b2a;

        float acc[8][8];
        #pragma unroll
        for (int t = 0; t < 8; ++t)
            #pragma unroll
            for (int c = 0; c < 8; ++c) acc[t][c] = 0.0f;

        float4 wreg[4];
        float4 xreg = make_float4(0.f, 0.f, 0.f, 0.f);

        auto load_chunk = [&](int kc) {
            #pragma unroll
            for (int p = 0; p < 4; ++p) {
                int f  = tid + p * 512;
                int k  = f >> 7;
                int c4 = (f & 127) << 2;
                wreg[p] = *(const float4*)&w1[(kc * 16 + k) * HHALF + c4];
            }
            if (tid < 256) {
                int t  = tid >> 2;
                int k4 = (tid & 3) << 2;
                xreg = *(const float4*)&xg[(size_t)(tok0 + t) * HDIM + kc * 16 + k4];
            }
        };

        load_chunk(0);
        for (int kc = 0; kc < HDIM / 16; ++kc) {
            __syncthreads();
            #pragma unroll
            for (int p = 0; p < 4; ++p) {
                int f  = tid + p * 512;
                int k  = f >> 7;
                int c4 = (f & 127) << 2;
                *(float4*)&sh_w[k][c4] = wreg[p];
            }
            if (tid < 256) {
                int t  = tid >> 2;
                int k4 = (tid & 3) << 2;
                sh_x[k4 + 0][t] = xreg.x;
                sh_x[k4 + 1][t] = xreg.y;
                sh_x[k4 + 2][t] = xreg.z;
                sh_x[k4 + 3][t] = xreg.w;
            }
            __syncthreads();
            if (kc + 1 < HDIM / 16) load_chunk(kc + 1);

            #pragma unroll 4
            for (int k = 0; k < 16; ++k) {
                float4 xa = *(const float4*)&sh_x[k][tg * 8];
                float4 xb = *(const float4*)&sh_x[k][tg * 8 + 4];
                float4 wa = *(const float4*)&sh_w[k][cA];
                float4 wb = *(const float4*)&sh_w[k][cB];
                float xs[8] = {xa.x, xa.y, xa.z, xa.w, xb.x, xb.y, xb.z, xb.w};
                float ws[8] = {wa.x, wa.y, wa.z, wa.w, wb.x, wb.y, wb.z, wb.w};
                #pragma unroll
                for (int t = 0; t < 8; ++t)
                    #pragma unroll
                    for (int c = 0; c < 8; ++c)
                        acc[t][c] = fmaf(xs[t], ws[c], acc[t][c]);
            }
        }

        {
            float4 bA4 = *(const float4*)&b1[cA];
            float4 bB4 = *(const float4*)&b1[cB];
            float bs[8] = {bA4.x, bA4.y, bA4.z, bA4.w, bB4.x, bB4.y, bB4.z, bB4.w};
            #pragma unroll
            for (int t = 0; t < 8; ++t)
                #pragma unroll
                for (int c = 0; c < 8; ++c)
                    acc[t][c] = gelu_exact(acc[t][c] + bs[c]);
        }

        for (int e = 0; e < NE; ++e) {
            float w2v[8];
            #pragma unroll
            for (int j = 0; j < 4; ++j) {
                w2v[j]     = w2[(cA + j) * NE + e];
                w2v[4 + j] = w2[(cB + j) * NE + e];
            }
            float bias2 = b2[e];
            #pragma unroll
            for (int t = 0; t < 8; ++t) {
                float s = 0.0f;
                #pragma unroll
                for (int j = 0; j < 8; ++j) s = fmaf(acc[t][j], w2v[j], s);
                #pragma unroll
                for (int off = 1; off < 64; off <<= 1)
                    s += __shfl_xor(s, off, 64);
                if (cg == 0) {
                    float raw   = s + bias2;
                    int   token = tok0 + tg * 8 + t;
                    out[(phase ? OFF_PH : OFF_PR) + (size_t)token * NE + e] = raw;
                }
            }
        }
    }
}

// ---------------------------------------------------------------------------
// Fallback per-token epilogue (only used with qir_mlp).
// ---------------------------------------------------------------------------
__global__ void __launch_bounds__(256)
qir_epilogue(const float* __restrict__ ent, float* __restrict__ out)
{
    __shared__ float sh_c[120], sh_s[120];
    const int tid = threadIdx.x;
    if (tid < 120) {
        int rem = tid, i = 0;
        while (rem >= 15 - i) { rem -= 15 - i; ++i; }
        int j = i + 1 + rem;
        float ang = ent[i * NE + j] * 0.5f;
        sh_c[tid] = cosf(ang);
        sh_s[tid] = sinf(ang);
    }
    __syncthreads();

    const int token = blockIdx.x * 256 + tid;

    #pragma unroll
    for (int q = 0; q < 4; ++q) {
        float4 v = *(const float4*)&out[OFF_PH + (size_t)token * NE + q * 4];
        v.x = tanhf(v.x) * PI_F;
        v.y = tanhf(v.y) * PI_F;
        v.z = tanhf(v.z) * PI_F;
        v.w = tanhf(v.w) * PI_F;
        *(float4*)&out[OFF_PH + (size_t)token * NE + q * 4] = v;
    }

    float a[16];
    #pragma unroll
    for (int q = 0; q < 4; ++q) {
        float4 v = *(const float4*)&out[OFF_PR + (size_t)token * NE + q * 4];
        a[q*4+0] = v.x; a[q*4+1] = v.y; a[q*4+2] = v.z; a[q*4+3] = v.w;
    }

    float m = fabsf(a[0]);
    #pragma unroll
    for (int e = 1; e < 16; ++e) m = fmaxf(m, fabsf(a[e]));
    float ssum = 0.0f;
    #pragma unroll
    for (int e = 0; e < 16; ++e) { a[e] = expf(fabsf(a[e]) - m); ssum += a[e]; }
    float inv = 1.0f / ssum;
    #pragma unroll
    for (int e = 0; e < 16; ++e) a[e] = sqrtf(a[e] * inv);

    {
        int p = 0;
        #pragma unroll
        for (int i = 0; i < 16; ++i) {
            #pragma unroll
            for (int j = i + 1; j < 16; ++j) {
                float c = sh_c[p], s = sh_s[p]; ++p;
                float ai = a[i], aj = a[j];
                a[i] = c * ai - s * aj;
                a[j] = s * ai + c * aj;
            }
        }
    }

    #pragma unroll
    for (int q = 0; q < 4; ++q)
        *(float4*)&out[OFF_DEC + (size_t)token * NE + q * 4] =
            make_float4(a[q*4], a[q*4+1], a[q*4+2], a[q*4+3]);

    float pr[16];
    float s2 = 0.0f;
    #pragma unroll
    for (int e = 0; e < 16; ++e) { pr[e] = a[e] * a[e]; s2 += pr[e]; }
    float inv2 = 1.0f / fmaxf(s2, 1e-12f);
    #pragma unroll
    for (int e = 0; e < 16; ++e) pr[e] *= inv2;
    #pragma unroll
    for (int q = 0; q < 4; ++q)
        *(float4*)&out[OFF_PR + (size_t)token * NE + q * 4] =
            make_float4(pr[q*4], pr[q*4+1], pr[q*4+2], pr[q*4+3]);

    float bv = pr[0]; int bi = 0;
    #pragma unroll
    for (int e = 1; e < 16; ++e) if (pr[e] > bv) { bv = pr[e]; bi = e; }
    float sv = -1.0f; int si = 0;
    #pragma unroll
    for (int e = 0; e < 16; ++e) if (e != bi && pr[e] > sv) { sv = pr[e]; si = e; }
    float ts = fmaxf(fabsf(bv) + fabsf(sv), 1e-12f);
    out[OFF_TP + (size_t)token * 2 + 0] = bv / ts;
    out[OFF_TP + (size_t)token * 2 + 1] = sv / ts;
    out[OFF_TI + (size_t)token * 2 + 0] = (float)bi;
    out[OFF_TI + (size_t)token * 2 + 1] = (float)si;
}

extern "C" void kernel_launch(void* const* d_in, const int* in_sizes, int n_in,
                              void* d_out, int out_size, void* d_ws, size_t ws_size,
                              hipStream_t stream) {
    const float* xg  = (const float*)d_in[0];
    const float* w1a = (const float*)d_in[1];
    const float* b1a = (const float*)d_in[2];
    const float* w2a = (const float*)d_in[3];
    const float* b2a = (const float*)d_in[4];
    const float* w1p = (const float*)d_in[5];
    const float* b1p = (const float*)d_in[6];
    const float* w2p = (const float*)d_in[7];
    const float* b2p = (const float*)d_in[8];
    const float* ent = (const float*)d_in[9];
    float* out = (float*)d_out;

    if (ws_size >= (size_t)4 * 1024 * 1024) {
        short* wt = (short*)d_ws;
        qir_wtrans<<<1024, 256, 0, stream>>>(w1a, w1p, wt);
        qir_gemm<<<1024, 256, 17408, stream>>>(xg, wt, b1a, w2a, b2a,
                                               b1p, w2p, b2p, ent, out);
    } else {
        qir_mlp<<<NTOK / 64, 512, 0, stream>>>(xg, w1a, b1a, w2a, b2a,
                                               w1p, b1p, w2p, b2p, out);
        qir_epilogue<<<NTOK / 256, 256, 0, stream>>>(ent, out);
    }
}